// Round 2
// baseline (251.084 us; speedup 1.0000x reference)
//
#include <hip/hip_runtime.h>
#include <cmath>

#define NPTS 262144
#define NLVL 16
#define NDENSE 5
#define NHASH 11
#define HASH_MASK 0x7FFFFu
#define P2 2654435761u
#define P3 805459861u

typedef float v2f __attribute__((ext_vector_type(2)));
typedef float v4f __attribute__((ext_vector_type(4)));
// 16B vector with 8B alignment guarantee (dense pair loads are only 8B-aligned)
typedef float v4f8 __attribute__((ext_vector_type(4), aligned(8)));

struct MetaD { float scale[NDENSE]; unsigned off[NDENSE]; unsigned res[NDENSE]; };
struct MetaH { float scale[NHASH]; unsigned off[NHASH]; };

struct Pt { float x, y, z; };

__device__ __forceinline__ Pt load_pt(const float* __restrict__ means, int p) {
    // plain loads: compiler merges to global_load_dwordx3; means stays L2-resident
    Pt q;
    q.x = (means[3 * p + 0] + 1.0f) * 0.5f;
    q.y = (means[3 * p + 1] + 1.0f) * 0.5f;
    q.z = (means[3 * p + 2] + 1.0f) * 0.5f;
    return q;
}

// ---------------- dense prep: 4 pair-base indices + weights ----------------
struct PrepD { unsigned b[4]; float fx; float wc[4]; };

__device__ __forceinline__ PrepD dprep(Pt q, float s, unsigned r, unsigned off) {
    const float px = q.x * s, py = q.y * s, pz = q.z * s;
    const float gx = floorf(px), gy = floorf(py), gz = floorf(pz);
    const float fx = px - gx, fy = py - gy, fz = pz - gz;
    const unsigned dy = r, dz = r * r;
    const unsigned base = (unsigned)gx + (unsigned)gy * dy + (unsigned)gz * dz + off;
    PrepD d;
    d.b[0] = base; d.b[1] = base + dy; d.b[2] = base + dz; d.b[3] = base + dz + dy;
    d.fx = fx;
    const float wy0 = 1.0f - fy, wz0 = 1.0f - fz;
    d.wc[0] = wz0 * wy0; d.wc[1] = wz0 * fy; d.wc[2] = fz * wy0; d.wc[3] = fz * fy;
    return d;
}

// ---------------- hash prep: yz hashes + even-x base ----------------
struct PrepH { unsigned hyz[4]; unsigned e, odd; float fx; float wc[4]; };

__device__ __forceinline__ PrepH hprep(Pt q, float s) {
    const float px = q.x * s, py = q.y * s, pz = q.z * s;
    const float gx = floorf(px), gy = floorf(py), gz = floorf(pz);
    const float fx = px - gx, fy = py - gy, fz = pz - gz;
    const unsigned ix = (unsigned)gx, iy = (unsigned)gy, iz = (unsigned)gz;
    PrepH d;
    const unsigned hy0 = iy * P2, hy1 = hy0 + P2;
    const unsigned hz0 = iz * P3, hz1 = hz0 + P3;
    d.hyz[0] = hy0 ^ hz0; d.hyz[1] = hy1 ^ hz0; d.hyz[2] = hy0 ^ hz1; d.hyz[3] = hy1 ^ hz1;
    d.e = ix & ~1u; d.odd = ix & 1u;
    d.fx = fx;
    const float wy0 = 1.0f - fy, wz0 = 1.0f - fz;
    d.wc[0] = wz0 * wy0; d.wc[1] = wz0 * fy; d.wc[2] = fz * wy0; d.wc[3] = fz * fy;
    return d;
}

// Evaluate one hash point from preloaded pair-quads F[4] and odd-extras G[4].
__device__ __forceinline__ v2f hfinish(const PrepH& d, const v4f* F, const v2f* G) {
    const float wx0 = 1.0f - d.fx;
    v2f acc = {0.0f, 0.0f};
#pragma unroll
    for (int c = 0; c < 4; ++c) {
        const v2f lo = {F[c].x, F[c].y};
        const v2f hi = {F[c].z, F[c].w};
        const bool sw = ((d.hyz[c] ^ d.odd) & 1u) != 0u;  // slot of x-corner ix
        const v2f c0 = sw ? hi : lo;
        const v2f c1 = d.odd ? G[c] : (sw ? lo : hi);
        acc += d.wc[c] * (wx0 * c0 + d.fx * c1);
    }
    return acc;
}

// ---------------- dense levels 0..4: 2 points/thread, paired float4 gathers ----------------
__global__ __launch_bounds__(256) void enc_dense(
    const float* __restrict__ means, const float* __restrict__ emb,
    v2f* __restrict__ dst, int lvl_major, MetaD meta)
{
    const int l = blockIdx.y;                    // wave-uniform level
    const int p0 = blockIdx.x * 512 + threadIdx.x;
    const float s = meta.scale[l];
    const unsigned off = meta.off[l];
    const unsigned r = meta.res[l];

    const PrepD A = dprep(load_pt(means, p0), s, r, off);
    const PrepD B = dprep(load_pt(means, p0 + 256), s, r, off);
    v4f8 FA[4], FB[4];
#pragma unroll
    for (int c = 0; c < 4; ++c) FA[c] = *(const v4f8*)(emb + 2u * A.b[c]);
#pragma unroll
    for (int c = 0; c < 4; ++c) FB[c] = *(const v4f8*)(emb + 2u * B.b[c]);

    v2f ra = {0.0f, 0.0f}, rb = {0.0f, 0.0f};
    const float ax0 = 1.0f - A.fx, bx0 = 1.0f - B.fx;
#pragma unroll
    for (int c = 0; c < 4; ++c) {
        ra += A.wc[c] * (ax0 * (v2f){FA[c].x, FA[c].y} + A.fx * (v2f){FA[c].z, FA[c].w});
        rb += B.wc[c] * (bx0 * (v2f){FB[c].x, FB[c].y} + B.fx * (v2f){FB[c].z, FB[c].w});
    }
    const size_t diA = lvl_major ? ((size_t)l * NPTS + p0) : ((size_t)p0 * NLVL + l);
    dst[diA] = ra;
    const size_t diB = lvl_major ? ((size_t)l * NPTS + p0 + 256) : ((size_t)(p0 + 256) * NLVL + l);
    dst[diB] = rb;
}

// ---------------- hash levels 5..15, XCD-affine, 704 jobs/XCD ----------------
__global__ __launch_bounds__(256) void enc_hash(
    const float* __restrict__ means, const float* __restrict__ emb,
    v2f* __restrict__ dst, int lvl_major, MetaH meta)
{
    const unsigned b = blockIdx.x;
    const unsigned xcd = b & 7u, slot = b >> 3;
    unsigned il, chunk;
    if (slot < 512u) { il = xcd; chunk = slot; }
    else {
        const unsigned g = xcd * 192u + (slot - 512u);   // 0..1535 over levels 8..10
        il = 8u + (g >> 9);
        chunk = g & 511u;
    }
    const float s = meta.scale[il];
    const unsigned off = meta.off[il];
    const unsigned lvl = il + NDENSE;
    const int p0 = (int)(chunk * 512u + threadIdx.x);
    const v2f* __restrict__ emb2 = (const v2f*)emb;

    const PrepH A = hprep(load_pt(means, p0), s);
    const PrepH B = hprep(load_pt(means, p0 + 256), s);

    // even-pair quads: base index (e^h)&M&~1 is even, off is even -> 16B aligned
    v4f FA[4], FB[4];
#pragma unroll
    for (int c = 0; c < 4; ++c) {
        const unsigned a = (A.e ^ A.hyz[c]) & HASH_MASK;
        FA[c] = *(const v4f*)(emb + 2u * (off + (a & ~1u)));
    }
#pragma unroll
    for (int c = 0; c < 4; ++c) {
        const unsigned a = (B.e ^ B.hyz[c]) & HASH_MASK;
        FB[c] = *(const v4f*)(emb + 2u * (off + (a & ~1u)));
    }
    // odd lanes additionally need corner e+2 (exec-masked: ~half the lanes)
    v2f GA[4] = {}, GB[4] = {};
    if (A.odd) {
#pragma unroll
        for (int c = 0; c < 4; ++c)
            GA[c] = emb2[off + (((A.e + 2u) ^ A.hyz[c]) & HASH_MASK)];
    }
    if (B.odd) {
#pragma unroll
        for (int c = 0; c < 4; ++c)
            GB[c] = emb2[off + (((B.e + 2u) ^ B.hyz[c]) & HASH_MASK)];
    }

    const v2f ra = hfinish(A, FA, GA);
    const size_t diA = lvl_major ? ((size_t)lvl * NPTS + p0) : ((size_t)p0 * NLVL + lvl);
    dst[diA] = ra;
    const v2f rb = hfinish(B, FB, GB);
    const size_t diB = lvl_major ? ((size_t)lvl * NPTS + (p0 + 256)) : ((size_t)(p0 + 256) * NLVL + lvl);
    dst[diB] = rb;
}

// ---------------- transpose ws[level][point] -> out[point][level] ----------------
__global__ __launch_bounds__(256) void transpose_out(
    const v2f* __restrict__ ws, float* __restrict__ out)
{
    const int p = blockIdx.x * 256 + threadIdx.x;
    v4f o[8];
    v2f* o2 = (v2f*)o;
#pragma unroll
    for (int l = 0; l < NLVL; ++l)
        o2[l] = __builtin_nontemporal_load(&ws[(size_t)l * NPTS + p]);  // single-use read
    v4f* out4 = (v4f*)(out + (size_t)p * (2 * NLVL));
#pragma unroll
    for (int k = 0; k < 8; ++k)
        __builtin_nontemporal_store(o[k], &out4[k]);                    // never re-read
}

extern "C" void kernel_launch(void* const* d_in, const int* in_sizes, int n_in,
                              void* d_out, int out_size, void* d_ws, size_t ws_size,
                              hipStream_t stream)
{
    const float* means = (const float*)d_in[0];
    const float* emb   = (const float*)d_in[1];
    float* out         = (float*)d_out;

    MetaD md;
    MetaH mh;
    const double lg = log2(1.38191288);
    unsigned off = 0;
    for (int l = 0; l < NLVL; ++l) {
        const double scale_d = pow(2.0, (double)l * lg) * 16.0 - 1.0;
        const unsigned res_enc = (unsigned)ceil(scale_d) + 1u;

        const double gres_d = ceil(16.0 * pow(1.38191288, (double)l));
        unsigned long long r3 = (unsigned long long)gres_d;
        r3 = r3 * r3 * r3;
        unsigned long long pl = r3 < (1ull << 19) ? r3 : (1ull << 19);
        pl = (pl + 7ull) / 8ull * 8ull;

        if (l < NDENSE) {
            md.scale[l] = (float)scale_d;
            md.off[l]   = off;
            md.res[l]   = res_enc;
        } else {
            mh.scale[l - NDENSE] = (float)scale_d;
            mh.off[l - NDENSE]   = off;
        }
        off += (unsigned)pl;
    }

    const size_t ws_needed = (size_t)NLVL * NPTS * sizeof(float) * 2;  // 32 MB
    const bool use_ws = ws_size >= ws_needed;
    v2f* dst = use_ws ? (v2f*)d_ws : (v2f*)out;
    const int lvl_major = use_ws ? 1 : 0;

    enc_dense<<<dim3(NPTS / 512, NDENSE, 1), 256, 0, stream>>>(means, emb, dst, lvl_major, md);
    enc_hash <<<dim3(8 * 704, 1, 1),          256, 0, stream>>>(means, emb, dst, lvl_major, mh);
    if (use_ws)
        transpose_out<<<NPTS / 256, 256, 0, stream>>>((const v2f*)d_ws, out);
}

// Round 3
// 210.699 us; speedup vs baseline: 1.1917x; 1.1917x over previous
//
#include <hip/hip_runtime.h>
#include <cmath>

#define NPTS 262144
#define NLVL 16
#define NDENSE 5
#define NHASH 11
#define HASH_MASK 0x7FFFFu
#define P2 2654435761u
#define P3 805459861u

typedef float v2f __attribute__((ext_vector_type(2)));
typedef float v4f __attribute__((ext_vector_type(4)));

struct MetaD { float scale[NDENSE]; unsigned off[NDENSE]; unsigned res[NDENSE]; };
struct MetaH { float scale[NHASH]; unsigned off[NHASH]; };

struct Pt { float x, y, z; };
struct Prep { unsigned idx[8]; float fx, fy, fz; };

// NT means load: protects XCD-L2-resident hash tables from the means stream (R1-measured win)
__device__ __forceinline__ Pt load_pt_nt(const float* __restrict__ means, int p) {
    Pt q;
    q.x = (__builtin_nontemporal_load(means + 3 * p + 0) + 1.0f) * 0.5f;
    q.y = (__builtin_nontemporal_load(means + 3 * p + 1) + 1.0f) * 0.5f;
    q.z = (__builtin_nontemporal_load(means + 3 * p + 2) + 1.0f) * 0.5f;
    return q;
}

// hash index prep (hsize = 2^19) — off folded into idx; branch-free (R1 structure)
__device__ __forceinline__ Prep hprep(Pt q, float s, unsigned off) {
    const float px = q.x * s, py = q.y * s, pz = q.z * s;
    const float gx = floorf(px), gy = floorf(py), gz = floorf(pz);
    Prep d;
    d.fx = px - gx; d.fy = py - gy; d.fz = pz - gz;
    const unsigned ix = (unsigned)gx, iy = (unsigned)gy, iz = (unsigned)gz;
    const unsigned hy0 = iy * P2, hy1 = hy0 + P2;
    const unsigned hz0 = iz * P3, hz1 = hz0 + P3;
    const unsigned h0 = hy0 ^ hz0, h1 = hy1 ^ hz0, h2 = hy0 ^ hz1, h3 = hy1 ^ hz1;
    d.idx[0] = ((ix ^ h0) & HASH_MASK) + off; d.idx[1] = (((ix + 1u) ^ h0) & HASH_MASK) + off;
    d.idx[2] = ((ix ^ h1) & HASH_MASK) + off; d.idx[3] = (((ix + 1u) ^ h1) & HASH_MASK) + off;
    d.idx[4] = ((ix ^ h2) & HASH_MASK) + off; d.idx[5] = (((ix + 1u) ^ h2) & HASH_MASK) + off;
    d.idx[6] = ((ix ^ h3) & HASH_MASK) + off; d.idx[7] = (((ix + 1u) ^ h3) & HASH_MASK) + off;
    return d;
}

__device__ __forceinline__ v2f trilerp(const v2f* f, float fx, float fy, float fz) {
    const float wx0 = 1.0f - fx, wy0 = 1.0f - fy, wz0 = 1.0f - fz;
    const float w00 = wz0 * wy0, w01 = wz0 * fy, w10 = fz * wy0, w11 = fz * fy;
    return w00 * (wx0 * f[0] + fx * f[1]) + w01 * (wx0 * f[2] + fx * f[3])
         + w10 * (wx0 * f[4] + fx * f[5]) + w11 * (wx0 * f[6] + fx * f[7]);
}

// ---------------- hash levels 5..15, XCD-affine, 704 balanced jobs/XCD (R1 exact) ----------------
__global__ __launch_bounds__(256) void enc_hash(
    const float* __restrict__ means, const float* __restrict__ emb,
    v2f* __restrict__ dst, int lvl_major, MetaH meta)
{
    const unsigned b = blockIdx.x;
    const unsigned xcd = b & 7u, slot = b >> 3;
    unsigned il, chunk;
    if (slot < 512u) { il = xcd; chunk = slot; }
    else {
        const unsigned g = xcd * 192u + (slot - 512u);   // 0..1535 over levels 8..10
        il = 8u + (g >> 9);
        chunk = g & 511u;
    }
    const float s = meta.scale[il];
    const unsigned off = meta.off[il];
    const unsigned lvl = il + NDENSE;
    const int p0 = (int)(chunk * 512u + threadIdx.x);
    const v2f* __restrict__ emb2 = (const v2f*)emb;

    const Prep A = hprep(load_pt_nt(means, p0), s, off);
    v2f fa[8];
#pragma unroll
    for (int k = 0; k < 8; ++k) fa[k] = emb2[A.idx[k]];
    const Prep B = hprep(load_pt_nt(means, p0 + 256), s, off);
    v2f fb[8];
#pragma unroll
    for (int k = 0; k < 8; ++k) fb[k] = emb2[B.idx[k]];

    const v2f ra = trilerp(fa, A.fx, A.fy, A.fz);
    const size_t diA = lvl_major ? ((size_t)lvl * NPTS + p0) : ((size_t)p0 * NLVL + lvl);
    dst[diA] = ra;
    const v2f rb = trilerp(fb, B.fx, B.fy, B.fz);
    const size_t diB = lvl_major ? ((size_t)lvl * NPTS + (p0 + 256)) : ((size_t)(p0 + 256) * NLVL + lvl);
    dst[diB] = rb;
}

// ---------------- fallback dense (point-major direct-to-out), R0 structure ----------------
__global__ __launch_bounds__(256) void enc_dense(
    const float* __restrict__ means, const float* __restrict__ emb,
    v2f* __restrict__ dst, int lvl_major, MetaD meta)
{
    const int p = blockIdx.x * 256 + threadIdx.x;
    const int l = blockIdx.y;

    const float x = (means[3 * p + 0] + 1.0f) * 0.5f;
    const float y = (means[3 * p + 1] + 1.0f) * 0.5f;
    const float z = (means[3 * p + 2] + 1.0f) * 0.5f;

    const float s = meta.scale[l];
    const unsigned off = meta.off[l];
    const unsigned r = meta.res[l];

    const float px = x * s, py = y * s, pz = z * s;
    const float gx = floorf(px), gy = floorf(py), gz = floorf(pz);
    const float fx = px - gx, fy = py - gy, fz = pz - gz;
    const unsigned base = (unsigned)gx + (unsigned)gy * r + (unsigned)gz * r * r + off;
    const unsigned dy = r, dz = r * r;

    const v2f* __restrict__ emb2 = (const v2f*)emb;
    v2f f[8];
    f[0] = emb2[base];           f[1] = emb2[base + 1];
    f[2] = emb2[base + dy];      f[3] = emb2[base + dy + 1];
    f[4] = emb2[base + dz];      f[5] = emb2[base + dz + 1];
    f[6] = emb2[base + dz + dy]; f[7] = emb2[base + dz + dy + 1];

    const v2f res = trilerp(f, fx, fy, fz);
    const size_t di = lvl_major ? ((size_t)l * NPTS + p) : ((size_t)p * NLVL + l);
    dst[di] = res;
}

// ---------------- fused finalize: dense levels inline + hash gather from ws ----------------
// Per point: issue 11 NT ws loads (hash results), compute 5 dense levels while in flight,
// write the 128B point-major row. NT on all streams keeps dense tables (~2MB) L2-resident.
__global__ __launch_bounds__(256) void finalize(
    const float* __restrict__ means, const float* __restrict__ emb,
    const v2f* __restrict__ ws, float* __restrict__ out, MetaD meta)
{
    const int p = blockIdx.x * 256 + threadIdx.x;

    v2f h[NHASH];
#pragma unroll
    for (int l = 0; l < NHASH; ++l)
        h[l] = __builtin_nontemporal_load(&ws[(size_t)(NDENSE + l) * NPTS + p]);

    const Pt q = load_pt_nt(means, p);

    v4f o[8];
    v2f* o2 = (v2f*)o;
#pragma unroll
    for (int l = 0; l < NDENSE; ++l) {
        const float s = meta.scale[l];
        const unsigned off = meta.off[l];
        const unsigned r = meta.res[l];
        const float px = q.x * s, py = q.y * s, pz = q.z * s;
        const float gx = floorf(px), gy = floorf(py), gz = floorf(pz);
        const float fx = px - gx, fy = py - gy, fz = pz - gz;
        const unsigned base = (unsigned)gx + (unsigned)gy * r + (unsigned)gz * r * r + off;
        const unsigned dy = r, dz = r * r;
        const v2f* __restrict__ emb2 = (const v2f*)emb;
        v2f f[8];
        f[0] = emb2[base];           f[1] = emb2[base + 1];
        f[2] = emb2[base + dy];      f[3] = emb2[base + dy + 1];
        f[4] = emb2[base + dz];      f[5] = emb2[base + dz + 1];
        f[6] = emb2[base + dz + dy]; f[7] = emb2[base + dz + dy + 1];
        o2[l] = trilerp(f, fx, fy, fz);
    }
#pragma unroll
    for (int l = 0; l < NHASH; ++l)
        o2[NDENSE + l] = h[l];

    v4f* out4 = (v4f*)(out + (size_t)p * (2 * NLVL));
#pragma unroll
    for (int k = 0; k < 8; ++k)
        __builtin_nontemporal_store(o[k], &out4[k]);
}

extern "C" void kernel_launch(void* const* d_in, const int* in_sizes, int n_in,
                              void* d_out, int out_size, void* d_ws, size_t ws_size,
                              hipStream_t stream)
{
    const float* means = (const float*)d_in[0];
    const float* emb   = (const float*)d_in[1];
    float* out         = (float*)d_out;

    MetaD md;
    MetaH mh;
    const double lg = log2(1.38191288);
    unsigned off = 0;
    for (int l = 0; l < NLVL; ++l) {
        const double scale_d = pow(2.0, (double)l * lg) * 16.0 - 1.0;
        const unsigned res_enc = (unsigned)ceil(scale_d) + 1u;

        const double gres_d = ceil(16.0 * pow(1.38191288, (double)l));
        unsigned long long r3 = (unsigned long long)gres_d;
        r3 = r3 * r3 * r3;
        unsigned long long pl = r3 < (1ull << 19) ? r3 : (1ull << 19);
        pl = (pl + 7ull) / 8ull * 8ull;

        if (l < NDENSE) {
            md.scale[l] = (float)scale_d;
            md.off[l]   = off;
            md.res[l]   = res_enc;
        } else {
            mh.scale[l - NDENSE] = (float)scale_d;
            mh.off[l - NDENSE]   = off;
        }
        off += (unsigned)pl;
    }

    const size_t ws_needed = (size_t)NLVL * NPTS * sizeof(float) * 2;  // 32 MB
    const bool use_ws = ws_size >= ws_needed;

    if (use_ws) {
        v2f* wsp = (v2f*)d_ws;
        enc_hash<<<dim3(8 * 704, 1, 1), 256, 0, stream>>>(means, emb, wsp, 1, mh);
        finalize<<<NPTS / 256, 256, 0, stream>>>(means, emb, (const v2f*)wsp, out, md);
    } else {
        v2f* dst = (v2f*)out;
        enc_dense<<<dim3(NPTS / 256, NDENSE, 1), 256, 0, stream>>>(means, emb, dst, 0, md);
        enc_hash <<<dim3(8 * 704, 1, 1),          256, 0, stream>>>(means, emb, dst, 0, mh);
    }
}